// Round 12
// baseline (182.619 us; speedup 1.0000x reference)
//
#include <hip/hip_runtime.h>

#define TT 52          // tag count incl START/STOP
#define NT 50          // normal tags
#define START_TAG 50
#define STOP_TAG 51
#define BB 1024
#define SS 512
#define BPSTR 64       // fallback kernel LDS bp row stride

__device__ __forceinline__ int seq_len(const void* mask, int b, int j) {
    int cnt = 0;
    const unsigned* w = (const unsigned*)mask;
    unsigned w0 = w[0];
    unsigned w1 = w[1];
    if (w0 == 0x01010101u) {                       // bool / uint8
        const unsigned char* m = (const unsigned char*)mask + (size_t)b * SS;
        for (int k = j; k < SS; k += 64) cnt += (m[k] != 0);
    } else if (w0 == 0x3f800000u) {                // float32
        const float* m = (const float*)mask + (size_t)b * SS;
        for (int k = j; k < SS; k += 64) cnt += (m[k] != 0.f);
    } else if (w1 == 1u) {                         // int32
        const int* m = (const int*)mask + (size_t)b * SS;
        for (int k = j; k < SS; k += 64) cnt += (m[k] != 0);
    } else {                                       // int64
        const long long* m = (const long long*)mask + (size_t)b * SS;
        for (int k = j; k < SS; k += 64) cnt += (m[k] != 0);
    }
    for (int off = 32; off; off >>= 1) cnt += __shfl_xor(cnt, off, 64);
    return cnt > 0 ? cnt : 1;
}

// One DP step (ambient: j, alpha, a_sh, A4, tt, acc):
// LDS broadcast (1 ds_write_b32 + 13 broadcast ds_read_b128), scalar adds,
// max3 tree (compiles to v_max3_f32), bv into acc.SLOT, alpha = bv + f.
// Single LDS buffer is WAR-safe (DS pipe executes a wave's ops in order).
// Bit-identical math to reference (same f32 adds, exact order-independent max).
#define DP_STEP(FREG, SLOT)                                                       \
    {                                                                             \
        a_sh[j] = alpha;                                                          \
        float q_[52];                                                             \
        _Pragma("unroll")                                                         \
        for (int r_ = 0; r_ < 13; ++r_) {                                         \
            float4 t4_ = A4[r_];                                                  \
            q_[4 * r_ + 0] = t4_.x; q_[4 * r_ + 1] = t4_.y;                       \
            q_[4 * r_ + 2] = t4_.z; q_[4 * r_ + 3] = t4_.w;                       \
        }                                                                         \
        float s_[NT];                                                             \
        _Pragma("unroll")                                                         \
        for (int i_ = 0; i_ < NT; ++i_) s_[i_] = q_[i_] + tt[i_];                 \
        float m_[17];                                                             \
        _Pragma("unroll")                                                         \
        for (int k_ = 0; k_ < 16; ++k_)                                           \
            m_[k_] = fmaxf(fmaxf(s_[3 * k_], s_[3 * k_ + 1]), s_[3 * k_ + 2]);    \
        m_[16] = fmaxf(s_[48], s_[49]);                                           \
        float n_[6];                                                              \
        _Pragma("unroll")                                                         \
        for (int k_ = 0; k_ < 5; ++k_)                                            \
            n_[k_] = fmaxf(fmaxf(m_[3 * k_], m_[3 * k_ + 1]), m_[3 * k_ + 2]);    \
        n_[5] = fmaxf(m_[15], m_[16]);                                            \
        float q0_ = fmaxf(fmaxf(n_[0], n_[1]), n_[2]);                            \
        float q1_ = fmaxf(fmaxf(n_[3], n_[4]), n_[5]);                            \
        float bv_ = fmaxf(q0_, q1_);                                              \
        acc.SLOT = bv_;                                                           \
        alpha = bv_ + (FREG);                                                     \
    }

// store acc (4 bv values) as one float4 at group GRP: ws4[b][GRP][j]
#define STORE4(GRP) { w4b[(size_t)(GRP) * 64] = acc; }

// value-match traceback step; ws layout [b][r>>2][j] float4, element r&3
#define TB_STEP_G(PTR, TPOS, BVC, BVS, FS, OB, WSF, FB, K)                        \
    {                                                                             \
        float bvp_ = BVS[K];                                                      \
        float ap_ = bvp_ + FS[K];                                                 \
        float cand_ = ap_ + trans_lds[jr + PTR];                                  \
        float cm_ = (j < NT) ? cand_ : -3.0e38f;                                  \
        float tgt_ = __builtin_bit_cast(float,                                    \
            __builtin_amdgcn_readlane(__builtin_bit_cast(int, BVC), PTR));        \
        unsigned long long bm_ = __ballot(cm_ == tgt_);                           \
        PTR = __ffsll(bm_) - 1;                                                   \
        --TPOS;                                                                   \
        OB[TPOS] = PTR;                                                           \
        BVC = bvp_;                                                               \
        int rc_ = TPOS - 4; rc_ = rc_ < 0 ? 0 : rc_;                              \
        BVS[K] = WSF[((rc_) >> 2) * 256 + (j << 2) + ((rc_) & 3)];                \
        FS[K] = FB[(size_t)rc_ * TT + jc];                                        \
    }

// ---------------- fast kernel: LDS-broadcast fwd, batched bv stores ---------
__global__ __launch_bounds__(64, 1) void crf_viterbi_fast1(
    const float* __restrict__ feats,   // [B,S,T]
    const void*  __restrict__ mask,    // [B,S]
    const float* __restrict__ trans,   // [T,T]
    float* __restrict__ ws,            // [B,128,64] float4 bv history (128 MiB)
    int* __restrict__ out)             // [B,S]
{
    __shared__ float trans_lds[64 * 53];            // [row i][col c], 53-padded
    __shared__ __align__(16) float a_sh[64];        // alpha broadcast (single buf)

    const int b = blockIdx.x;
    const int j = threadIdx.x;
    const int jc = j < NT ? j : NT - 1;
    const int jr = j * 53;
    const float4* A4 = (const float4*)a_sh;

    // stage trans rows into LDS (traceback use); rows >= NT get -inf sentinel
    for (int k = j; k < 64 * 53; k += 64) {
        int r = k / 53, c = k - r * 53;
        float v = -3.0e38f;
        if (r < NT && c < TT) v = trans[r * TT + c];
        trans_lds[k] = v;
    }

    const int len = seq_len(mask, b, j);

    // transition column trans[0..49][j] into registers
    float tt[NT];
#pragma unroll
    for (int i = 0; i < NT; ++i) tt[i] = trans[i * TT + j];  // j<=63 in bounds

    // init (pos 0): alpha0 = bv0 + f0 with bv0 = trans[START][j]
    const float* fp = feats + ((size_t)b * SS) * TT + jc;
    float4* w4b = (float4*)ws + (size_t)b * (SS / 4) * 64 + j;
    const float bvi = trans[START_TAG * TT + jc];
    float alpha = bvi + fp[0];
    float4 acc = make_float4(bvi, bvi, bvi, bvi);   // slot x = pos 0

#define FLD(P) fp[(size_t)((P) < SS ? (P) : SS - 1) * TT]
    // 8-deep feats prefetch; invariant at loop top (pos ≡ 1 mod 8):
    // fA = f[pos..pos+3], fB = f[pos+4..pos+7]
    float fA0 = FLD(1), fA1 = FLD(2), fA2 = FLD(3), fA3 = FLD(4);
    float fB0 = FLD(5), fB1 = FLD(6), fB2 = FLD(7), fB3 = FLD(8);

    int pos = 1;
    for (; pos + 7 < len; pos += 8) {
        DP_STEP(fA0, y)                      // step pos+0, slot 1
        DP_STEP(fA1, z)                      // step pos+1, slot 2
        DP_STEP(fA2, w) STORE4((pos + 2) >> 2)  // step pos+2, slot 3 -> group
        DP_STEP(fA3, x)                      // step pos+3, slot 0
        fA0 = FLD(pos + 8);  fA1 = FLD(pos + 9);
        fA2 = FLD(pos + 10); fA3 = FLD(pos + 11);
        DP_STEP(fB0, y)                      // step pos+4
        DP_STEP(fB1, z)                      // step pos+5
        DP_STEP(fB2, w) STORE4((pos + 6) >> 2)  // step pos+6
        DP_STEP(fB3, x)                      // step pos+7
        fB0 = FLD(pos + 12); fB1 = FLD(pos + 13);
        fB2 = FLD(pos + 14); fB3 = FLD(pos + 15);
    }
    // tail (pos ≡ 1 mod 8): same slot pattern, k = 0..6
    if (pos < len) { DP_STEP(fA0, y) ++pos; }
    if (pos < len) { DP_STEP(fA1, z) ++pos; }
    if (pos < len) { DP_STEP(fA2, w) STORE4(pos >> 2) ++pos; }
    if (pos < len) { DP_STEP(fA3, x) ++pos; }
    if (pos < len) { DP_STEP(fB0, y) ++pos; }
    if (pos < len) { DP_STEP(fB1, z) ++pos; }
    if (pos < len) { DP_STEP(fB2, w) STORE4(pos >> 2) ++pos; }
    // final (possibly partial) group; stale high slots are never read (r < len)
    STORE4((len - 1) >> 2)
#undef FLD

    // ---- best last tag ----
    float v = alpha + trans[jc * TT + STOP_TAG];
    if (j >= NT) v = -3.0e38f;
    int idxb = j < NT ? j : 0;
    for (int off = 32; off; off >>= 1) {
        float vo = __shfl_xor(v, off, 64);
        int   io = __shfl_xor(idxb, off, 64);
        if (vo > v || (vo == v && io < idxb)) { v = vo; idxb = io; }
    }

    __syncthreads();   // trans_lds visibility (one-time, cheap)

    // ---- traceback by value matching ----
    int ptr = idxb;
    int* ob = out + (size_t)b * SS;
    ob[len - 1] = ptr;

    const float* wsf = ws + (size_t)b * (SS / 4) * 256;   // float view of ws4[b]
    const float* fbase = feats + ((size_t)b * SS) * TT;   // + r*TT + jc

    float bvs[4], fs[4];
    float bvc;
    {
        int r0 = len - 1;
        bvc = wsf[(r0 >> 2) * 256 + (j << 2) + (r0 & 3)];
#pragma unroll
        for (int k = 0; k < 4; ++k) {
            int r = len - 2 - k; int rc = r < 0 ? 0 : r;
            bvs[k] = wsf[(rc >> 2) * 256 + (j << 2) + (rc & 3)];
            fs[k]  = fbase[(size_t)rc * TT + jc];
        }
    }

    int tpos = len - 1;
    while (tpos >= 4) {
        TB_STEP_G(ptr, tpos, bvc, bvs, fs, ob, wsf, fbase, 0)
        TB_STEP_G(ptr, tpos, bvc, bvs, fs, ob, wsf, fbase, 1)
        TB_STEP_G(ptr, tpos, bvc, bvs, fs, ob, wsf, fbase, 2)
        TB_STEP_G(ptr, tpos, bvc, bvs, fs, ob, wsf, fbase, 3)
    }
    if (tpos >= 1) TB_STEP_G(ptr, tpos, bvc, bvs, fs, ob, wsf, fbase, 0)
    if (tpos >= 1) TB_STEP_G(ptr, tpos, bvc, bvs, fs, ob, wsf, fbase, 1)
    if (tpos >= 1) TB_STEP_G(ptr, tpos, bvc, bvs, fs, ob, wsf, fbase, 2)

    // zero-fill positions >= len
    for (int p = len + j; p < SS; p += 64) ob[p] = 0;
}

// ---------------- fallback (round-2 proven kernel, no workspace) ------------
__global__ __launch_bounds__(64, 1) void crf_viterbi(
    const float* __restrict__ feats,
    const void*  __restrict__ mask,
    const float* __restrict__ trans,
    int* __restrict__ out)
{
    __shared__ unsigned char bp_sh[SS * BPSTR];

    const int b = blockIdx.x;
    const int j = threadIdx.x;
    const int jc = j < NT ? j : NT - 1;

    const int len = seq_len(mask, b, j);

    float tt[NT];
#pragma unroll
    for (int i = 0; i < NT; ++i) tt[i] = trans[i * TT + j];

    const float* fp = feats + ((size_t)b * SS) * TT + jc;
    float alpha = trans[START_TAG * TT + jc] + fp[0];
    float fnext = fp[TT];

    for (int pos = 1; pos < len; ++pos) {
        const float f = fnext;
        { int np = pos + 1 < SS ? pos + 1 : SS - 1; fnext = fp[(size_t)np * TT]; }

        float best[4] = { -3.0e38f, -3.0e38f, -3.0e38f, -3.0e38f };
        int   bidx[4] = { 0, 0, 0, 0 };
        const int abits = __builtin_bit_cast(int, alpha);
#pragma unroll
        for (int i = 0; i < NT; ++i) {
            int ab = __builtin_amdgcn_readlane(abits, i);
            float s = __builtin_bit_cast(float, ab) + tt[i];
            const int c = i & 3;
            if (s > best[c]) { best[c] = s; bidx[c] = i; }
        }
        float bv = best[0]; int bi = bidx[0];
        if (best[1] > bv || (best[1] == bv && bidx[1] < bi)) { bv = best[1]; bi = bidx[1]; }
        if (best[2] > bv || (best[2] == bv && bidx[2] < bi)) { bv = best[2]; bi = bidx[2]; }
        if (best[3] > bv || (best[3] == bv && bidx[3] < bi)) { bv = best[3]; bi = bidx[3]; }

        alpha = bv + f;
        bp_sh[pos * BPSTR + j] = (unsigned char)bi;
    }

    float v = alpha + trans[jc * TT + STOP_TAG];
    if (j >= NT) v = -3.0e38f;
    int idx = j < NT ? j : 0;
    for (int off = 32; off; off >>= 1) {
        float vo = __shfl_xor(v, off, 64);
        int   io = __shfl_xor(idx, off, 64);
        if (vo > v || (vo == v && io < idx)) { v = vo; idx = io; }
    }

    __syncthreads();

    int ptr = idx;
    int* ob = out + (size_t)b * SS;
    for (int pos = len - 1; pos >= 1; --pos) {
        if (j == 0) ob[pos] = ptr;
        ptr = (int)bp_sh[pos * BPSTR + ptr];
    }
    if (j == 0) ob[0] = ptr;

    for (int p = len + j; p < SS; p += 64) ob[p] = 0;
}

extern "C" void kernel_launch(void* const* d_in, const int* in_sizes, int n_in,
                              void* d_out, int out_size, void* d_ws, size_t ws_size,
                              hipStream_t stream) {
    const float* feats = (const float*)d_in[0];
    const void*  mask  = d_in[1];
    // d_in[2] = tags, unused
    const float* trans = (const float*)d_in[3];
    int* out = (int*)d_out;

    const size_t need = (size_t)BB * SS * 64 * sizeof(float);   // 128 MiB
    if (ws_size >= need) {
        crf_viterbi_fast1<<<dim3(BB), dim3(64), 0, stream>>>(feats, mask, trans,
                                                             (float*)d_ws, out);
    } else {
        crf_viterbi<<<dim3(BB), dim3(64), 0, stream>>>(feats, mask, trans, out);
    }
}

// Round 13
// 179.317 us; speedup vs baseline: 1.0184x; 1.0184x over previous
//
#include <hip/hip_runtime.h>

#define TT 52          // tag count incl START/STOP
#define NT 50          // normal tags
#define START_TAG 50
#define STOP_TAG 51
#define BB 1024
#define SS 512
#define BPSTR 64       // fallback kernel LDS bp row stride

__device__ __forceinline__ int seq_len(const void* mask, int b, int j) {
    int cnt = 0;
    const unsigned* w = (const unsigned*)mask;
    unsigned w0 = w[0];
    unsigned w1 = w[1];
    if (w0 == 0x01010101u) {                       // bool / uint8
        const unsigned char* m = (const unsigned char*)mask + (size_t)b * SS;
        for (int k = j; k < SS; k += 64) cnt += (m[k] != 0);
    } else if (w0 == 0x3f800000u) {                // float32
        const float* m = (const float*)mask + (size_t)b * SS;
        for (int k = j; k < SS; k += 64) cnt += (m[k] != 0.f);
    } else if (w1 == 1u) {                         // int32
        const int* m = (const int*)mask + (size_t)b * SS;
        for (int k = j; k < SS; k += 64) cnt += (m[k] != 0);
    } else {                                       // int64
        const long long* m = (const long long*)mask + (size_t)b * SS;
        for (int k = j; k < SS; k += 64) cnt += (m[k] != 0);
    }
    for (int off = 32; off; off >>= 1) cnt += __shfl_xor(cnt, off, 64);
    return cnt > 0 ? cnt : 1;
}

// ---- DPP all-gather pieces -------------------------------------------------
// row_ror:k (ctrl 0x120|k) is a bijective rotation within each 16-lane row.
// The exact direction is irrelevant: pk_[k] (probed with the lane index as
// payload) records which lane's value arrives, and tt_ is loaded to match.
#define RR(R, K, BREG)                                                            \
    s_[16 * (R) + (K)] = __builtin_bit_cast(float,                                \
        __builtin_amdgcn_mov_dpp((BREG), 0x120 | (K), 0xF, 0xF, true))            \
        + tt_[R][K];

#define EXPAND16(R, BREG)                                                         \
    s_[16 * (R) + 0] = __builtin_bit_cast(float, (BREG)) + tt_[R][0];             \
    RR(R, 1, BREG)  RR(R, 2, BREG)  RR(R, 3, BREG)  RR(R, 4, BREG)               \
    RR(R, 5, BREG)  RR(R, 6, BREG)  RR(R, 7, BREG)  RR(R, 8, BREG)               \
    RR(R, 9, BREG)  RR(R, 10, BREG) RR(R, 11, BREG) RR(R, 12, BREG)              \
    RR(R, 13, BREG) RR(R, 14, BREG) RR(R, 15, BREG)

// One DP step (ambient: j, alpha, tt_, wsb): all-gather alpha via
// 3 shfl_xor + 60 DPP movs (VALU), 64 adds, exact max3 tree, store bv,
// alpha = bv + f. Sources i>=NT are masked by tt_=-3e38 (junk lane alphas
// stay finite, can never win). Max is exact & order-independent and the adds
// are the reference's f32 ops => bv/alpha bit-identical to the scan.
#define DP_STEP(FREG, POSV)                                                       \
    {                                                                             \
        const int ab_ = __builtin_bit_cast(int, alpha);                           \
        const int b1_ = __shfl_xor(ab_, 16, 64);                                  \
        const int b2_ = __shfl_xor(ab_, 32, 64);                                  \
        const int b3_ = __shfl_xor(ab_, 48, 64);                                  \
        float s_[64];                                                             \
        EXPAND16(0, ab_) EXPAND16(1, b1_) EXPAND16(2, b2_) EXPAND16(3, b3_)       \
        float m_[21];                                                             \
        _Pragma("unroll")                                                         \
        for (int q_ = 0; q_ < 21; ++q_)                                           \
            m_[q_] = fmaxf(fmaxf(s_[3 * q_], s_[3 * q_ + 1]), s_[3 * q_ + 2]);    \
        float n_[7];                                                              \
        _Pragma("unroll")                                                         \
        for (int q_ = 0; q_ < 7; ++q_)                                            \
            n_[q_] = fmaxf(fmaxf(m_[3 * q_], m_[3 * q_ + 1]), m_[3 * q_ + 2]);    \
        float t0_ = fmaxf(fmaxf(n_[0], n_[1]), n_[2]);                            \
        float t1_ = fmaxf(fmaxf(n_[3], n_[4]), n_[5]);                            \
        float t2_ = fmaxf(n_[6], s_[63]);                                         \
        float bv_ = fmaxf(fmaxf(t0_, t1_), t2_);                                  \
        wsb[(size_t)(POSV) * 64] = bv_;                                           \
        alpha = bv_ + (FREG);                                                     \
    }

// value-match traceback step (ambient: j, jc, jr, trans_lds)
#define TB_STEP_G(PTR, TPOS, BVC, BVS, FS, OB, WSR, FB, K)                        \
    {                                                                             \
        float bvp_ = BVS[K];                                                      \
        float ap_ = bvp_ + FS[K];                                                 \
        float cand_ = ap_ + trans_lds[jr + PTR];                                  \
        float cm_ = (j < NT) ? cand_ : -3.0e38f;                                  \
        float tgt_ = __builtin_bit_cast(float,                                    \
            __builtin_amdgcn_readlane(__builtin_bit_cast(int, BVC), PTR));        \
        unsigned long long bm_ = __ballot(cm_ == tgt_);                           \
        PTR = __ffsll(bm_) - 1;                                                   \
        --TPOS;                                                                   \
        OB[TPOS] = PTR;                                                           \
        BVC = bvp_;                                                               \
        int rc_ = TPOS - 4; rc_ = rc_ < 0 ? 0 : rc_;                              \
        BVS[K] = WSR[(size_t)rc_ * 64 + j];                                       \
        FS[K] = FB[(size_t)rc_ * TT + jc];                                        \
    }

// ---------------- fast kernel: DPP all-gather fwd; value-match traceback ----
__global__ __launch_bounds__(64, 1) void crf_viterbi_fast1(
    const float* __restrict__ feats,   // [B,S,T]
    const void*  __restrict__ mask,    // [B,S]
    const float* __restrict__ trans,   // [T,T]
    float* __restrict__ ws,            // [B,S,64] bv history (128 MiB)
    int* __restrict__ out)             // [B,S]
{
    __shared__ float trans_lds[64 * 53];            // [row i][col c], 53-padded

    const int b = blockIdx.x;
    const int j = threadIdx.x;
    const int jc = j < NT ? j : NT - 1;
    const int jr = j * 53;

    // stage trans rows into LDS (traceback use); rows >= NT get -inf sentinel
    for (int k = j; k < 64 * 53; k += 64) {
        int r = k / 53, c = k - r * 53;
        float v = -3.0e38f;
        if (r < NT && c < TT) v = trans[r * TT + c];
        trans_lds[k] = v;
    }

    const int len = seq_len(mask, b, j);

    // ---- probe the DPP row-rotation maps (payload = lane index) ----
    int pk_[16];
    pk_[0] = j;
    pk_[1]  = __builtin_amdgcn_mov_dpp(j, 0x121, 0xF, 0xF, true);
    pk_[2]  = __builtin_amdgcn_mov_dpp(j, 0x122, 0xF, 0xF, true);
    pk_[3]  = __builtin_amdgcn_mov_dpp(j, 0x123, 0xF, 0xF, true);
    pk_[4]  = __builtin_amdgcn_mov_dpp(j, 0x124, 0xF, 0xF, true);
    pk_[5]  = __builtin_amdgcn_mov_dpp(j, 0x125, 0xF, 0xF, true);
    pk_[6]  = __builtin_amdgcn_mov_dpp(j, 0x126, 0xF, 0xF, true);
    pk_[7]  = __builtin_amdgcn_mov_dpp(j, 0x127, 0xF, 0xF, true);
    pk_[8]  = __builtin_amdgcn_mov_dpp(j, 0x128, 0xF, 0xF, true);
    pk_[9]  = __builtin_amdgcn_mov_dpp(j, 0x129, 0xF, 0xF, true);
    pk_[10] = __builtin_amdgcn_mov_dpp(j, 0x12A, 0xF, 0xF, true);
    pk_[11] = __builtin_amdgcn_mov_dpp(j, 0x12B, 0xF, 0xF, true);
    pk_[12] = __builtin_amdgcn_mov_dpp(j, 0x12C, 0xF, 0xF, true);
    pk_[13] = __builtin_amdgcn_mov_dpp(j, 0x12D, 0xF, 0xF, true);
    pk_[14] = __builtin_amdgcn_mov_dpp(j, 0x12E, 0xF, 0xF, true);
    pk_[15] = __builtin_amdgcn_mov_dpp(j, 0x12F, 0xF, 0xF, true);

    // ---- matched transition coefficients: tt_[r][k] pairs with source
    // i = pk_[k] ^ 16r whose value lands in slot (r,k) of the all-gather ----
    float tt_[4][16];
#pragma unroll
    for (int r = 0; r < 4; ++r) {
#pragma unroll
        for (int k = 0; k < 16; ++k) {
            int i = pk_[k] ^ (r << 4);
            tt_[r][k] = (i < NT) ? trans[i * TT + j] : -3.0e38f;  // idx<=2611<2704
        }
    }

    // init (pos 0): alpha0 = bv0 + f0 with bv0 = trans[START][j]
    const float* fp = feats + ((size_t)b * SS) * TT + jc;
    float* wsb = ws + ((size_t)b * SS) * 64 + j;
    const float bvi = trans[START_TAG * TT + jc];
    float alpha = bvi + fp[0];
    wsb[0] = bvi;

#define FLD(P) fp[(size_t)((P) < SS ? (P) : SS - 1) * TT]
    // 8-deep feats prefetch; invariant at loop top:
    // fA = f[pos..pos+3], fB = f[pos+4..pos+7]
    float fA0 = FLD(1), fA1 = FLD(2), fA2 = FLD(3), fA3 = FLD(4);
    float fB0 = FLD(5), fB1 = FLD(6), fB2 = FLD(7), fB3 = FLD(8);

    int pos = 1;
    for (; pos + 7 < len; pos += 8) {
        DP_STEP(fA0, pos + 0)
        DP_STEP(fA1, pos + 1)
        DP_STEP(fA2, pos + 2)
        DP_STEP(fA3, pos + 3)
        fA0 = FLD(pos + 8);  fA1 = FLD(pos + 9);
        fA2 = FLD(pos + 10); fA3 = FLD(pos + 11);
        DP_STEP(fB0, pos + 4)
        DP_STEP(fB1, pos + 5)
        DP_STEP(fB2, pos + 6)
        DP_STEP(fB3, pos + 7)
        fB0 = FLD(pos + 12); fB1 = FLD(pos + 13);
        fB2 = FLD(pos + 14); fB3 = FLD(pos + 15);
    }
    // tail: fA = f[pos..pos+3], fB = f[pos+4..pos+7]; up to 7 steps remain
    if (pos < len) { DP_STEP(fA0, pos) ++pos; }
    if (pos < len) { DP_STEP(fA1, pos) ++pos; }
    if (pos < len) { DP_STEP(fA2, pos) ++pos; }
    if (pos < len) { DP_STEP(fA3, pos) ++pos; }
    if (pos < len) { DP_STEP(fB0, pos) ++pos; }
    if (pos < len) { DP_STEP(fB1, pos) ++pos; }
    if (pos < len) { DP_STEP(fB2, pos) ++pos; }
#undef FLD

    // ---- best last tag ----
    float v = alpha + trans[jc * TT + STOP_TAG];
    if (j >= NT) v = -3.0e38f;
    int idxb = j < NT ? j : 0;
    for (int off = 32; off; off >>= 1) {
        float vo = __shfl_xor(v, off, 64);
        int   io = __shfl_xor(idxb, off, 64);
        if (vo > v || (vo == v && io < idxb)) { v = vo; idxb = io; }
    }

    __syncthreads();   // trans_lds visibility (one-time, cheap)

    // ---- traceback by value matching ----
    int ptr = idxb;
    int* ob = out + (size_t)b * SS;
    ob[len - 1] = ptr;

    const float* wsr = ws + ((size_t)b * SS) * 64;        // + r*64 + j
    const float* fbase = feats + ((size_t)b * SS) * TT;   // + r*TT + jc

    float bvs[4], fs[4];
    float bvc = wsr[(size_t)(len - 1) * 64 + j];
#pragma unroll
    for (int k = 0; k < 4; ++k) {
        int r = len - 2 - k; int rc = r < 0 ? 0 : r;
        bvs[k] = wsr[(size_t)rc * 64 + j];
        fs[k]  = fbase[(size_t)rc * TT + jc];
    }

    int tpos = len - 1;
    while (tpos >= 4) {
        TB_STEP_G(ptr, tpos, bvc, bvs, fs, ob, wsr, fbase, 0)
        TB_STEP_G(ptr, tpos, bvc, bvs, fs, ob, wsr, fbase, 1)
        TB_STEP_G(ptr, tpos, bvc, bvs, fs, ob, wsr, fbase, 2)
        TB_STEP_G(ptr, tpos, bvc, bvs, fs, ob, wsr, fbase, 3)
    }
    if (tpos >= 1) TB_STEP_G(ptr, tpos, bvc, bvs, fs, ob, wsr, fbase, 0)
    if (tpos >= 1) TB_STEP_G(ptr, tpos, bvc, bvs, fs, ob, wsr, fbase, 1)
    if (tpos >= 1) TB_STEP_G(ptr, tpos, bvc, bvs, fs, ob, wsr, fbase, 2)

    // zero-fill positions >= len
    for (int p = len + j; p < SS; p += 64) ob[p] = 0;
}

// ---------------- fallback (round-2 proven kernel, no workspace) ------------
__global__ __launch_bounds__(64, 1) void crf_viterbi(
    const float* __restrict__ feats,
    const void*  __restrict__ mask,
    const float* __restrict__ trans,
    int* __restrict__ out)
{
    __shared__ unsigned char bp_sh[SS * BPSTR];

    const int b = blockIdx.x;
    const int j = threadIdx.x;
    const int jc = j < NT ? j : NT - 1;

    const int len = seq_len(mask, b, j);

    float tt[NT];
#pragma unroll
    for (int i = 0; i < NT; ++i) tt[i] = trans[i * TT + j];

    const float* fp = feats + ((size_t)b * SS) * TT + jc;
    float alpha = trans[START_TAG * TT + jc] + fp[0];
    float fnext = fp[TT];

    for (int pos = 1; pos < len; ++pos) {
        const float f = fnext;
        { int np = pos + 1 < SS ? pos + 1 : SS - 1; fnext = fp[(size_t)np * TT]; }

        float best[4] = { -3.0e38f, -3.0e38f, -3.0e38f, -3.0e38f };
        int   bidx[4] = { 0, 0, 0, 0 };
        const int abits = __builtin_bit_cast(int, alpha);
#pragma unroll
        for (int i = 0; i < NT; ++i) {
            int ab = __builtin_amdgcn_readlane(abits, i);
            float s = __builtin_bit_cast(float, ab) + tt[i];
            const int c = i & 3;
            if (s > best[c]) { best[c] = s; bidx[c] = i; }
        }
        float bv = best[0]; int bi = bidx[0];
        if (best[1] > bv || (best[1] == bv && bidx[1] < bi)) { bv = best[1]; bi = bidx[1]; }
        if (best[2] > bv || (best[2] == bv && bidx[2] < bi)) { bv = best[2]; bi = bidx[2]; }
        if (best[3] > bv || (best[3] == bv && bidx[3] < bi)) { bv = best[3]; bi = bidx[3]; }

        alpha = bv + f;
        bp_sh[pos * BPSTR + j] = (unsigned char)bi;
    }

    float v = alpha + trans[jc * TT + STOP_TAG];
    if (j >= NT) v = -3.0e38f;
    int idx = j < NT ? j : 0;
    for (int off = 32; off; off >>= 1) {
        float vo = __shfl_xor(v, off, 64);
        int   io = __shfl_xor(idx, off, 64);
        if (vo > v || (vo == v && io < idx)) { v = vo; idx = io; }
    }

    __syncthreads();

    int ptr = idx;
    int* ob = out + (size_t)b * SS;
    for (int pos = len - 1; pos >= 1; --pos) {
        if (j == 0) ob[pos] = ptr;
        ptr = (int)bp_sh[pos * BPSTR + ptr];
    }
    if (j == 0) ob[0] = ptr;

    for (int p = len + j; p < SS; p += 64) ob[p] = 0;
}

extern "C" void kernel_launch(void* const* d_in, const int* in_sizes, int n_in,
                              void* d_out, int out_size, void* d_ws, size_t ws_size,
                              hipStream_t stream) {
    const float* feats = (const float*)d_in[0];
    const void*  mask  = d_in[1];
    // d_in[2] = tags, unused
    const float* trans = (const float*)d_in[3];
    int* out = (int*)d_out;

    const size_t need = (size_t)BB * SS * 64 * sizeof(float);   // 128 MiB
    if (ws_size >= need) {
        crf_viterbi_fast1<<<dim3(BB), dim3(64), 0, stream>>>(feats, mask, trans,
                                                             (float*)d_ws, out);
    } else {
        crf_viterbi<<<dim3(BB), dim3(64), 0, stream>>>(feats, mask, trans, out);
    }
}